// Round 5
// baseline (256.300 us; speedup 1.0000x reference)
//
#include <hip/hip_runtime.h>

#define KSIZE 7
#define NEG_INF (-1e30f)
#define IMG_H 512
#define IMG_W 512
#define TILE_W 256             // 64 lanes x 4 cols, one wave per block
#define STRIPE 32              // output rows per block
#define ROW_DW 264             // dwords per LDS row: 256 data + 4+4 halo
#define RING 8                 // LDS row ring (power of two), wave-private

// <2 x float> — fadd lowers to v_pk_add_f32 on gfx90a+ (packed fp32 ops)
typedef float pk2 __attribute__((ext_vector_type(2)));

// fmaxf(a, fmaxf(b, c)) -> v_max3_f32
#define M3(a, b, c) fmaxf((a), fmaxf((b), (c)))

static __device__ __forceinline__ pk2 mk2(float a, float b) {
    pk2 r; r.x = a; r.y = b; return r;
}

// One filter-row contribution to one output: taps t_j = v[1+l+j] + f[j].
// Pairs (j,j+1) for j=0,2,4 packed; j=6 scalar. Max tree exactly equal in
// value to the scalar form (max associative/commutative; adds identical).
static __device__ __forceinline__ float dil_body(float acc, pk2 a, pk2 b, pk2 c,
                                                 float t6v, pk2 f01, pk2 f23,
                                                 pk2 f45, float f6) {
    const pk2 t01 = a + f01;          // v_pk_add_f32
    const pk2 t23 = b + f23;
    const pk2 t45 = c + f45;
    const float t6 = t6v + f6;
    const float u = M3(t01.x, t01.y, t23.x);
    const float w = M3(t23.y, t45.x, t45.y);
    const float z = M3(acc, t6, u);
    return fmaxf(z, w);
}

// Single-wave block: no __syncthreads anywhere. The LDS ring is wave-private;
// same-wave ds ops to aliasing addresses execute in order (compiler preserves
// program order + inserts lgkmcnt since ring slots provably alias).
__global__ __launch_bounds__(64)
void GrayscaleDilation2D_kernel(const float* __restrict__ img,
                                const float* __restrict__ filt,
                                float* __restrict__ out) {
    __shared__ float ring[RING * ROW_DW];   // 8448 B -> 16 blocks/CU by LDS

    const int plane = blockIdx.z;
    const int x0 = blockIdx.x * TILE_W;
    const int y0 = blockIdx.y * STRIPE;     // y0 % 8 == 0 (slot math relies on it)
    const float* __restrict__ src = img + (size_t)plane * IMG_H * IMG_W;
    float* __restrict__ dst = out + (size_t)plane * IMG_H * IMG_W;

    const int lane = threadIdx.x;           // 0..63
    const int cd = lane * 4;                // dword base within a ring row
    // Rows fetched: y0-3 .. y0+34 (clamped). Beyond -> NEG_INF staged.
    const int ymax = (y0 + STRIPE + 3 < IMG_H) ? (y0 + STRIPE + 3) : IMG_H;

    // Filter prepacked as pairs + scalar; uniform const-index loads -> SGPRs.
    pk2 fp[KSIZE][3];
    float f6[KSIZE];
#pragma unroll
    for (int i = 0; i < KSIZE; ++i) {
        const float* fr = filt + i * KSIZE;
        fp[i][0] = mk2(fr[0], fr[1]);
        fp[i][1] = mk2(fr[2], fr[3]);
        fp[i][2] = mk2(fr[4], fr[5]);
        f6[i] = fr[6];
    }

    const float4 NI4 = make_float4(NEG_INF, NEG_INF, NEG_INF, NEG_INF);
    // Stage registers: one 8-row chunk in flight (T14 issue-early/write-late).
    // Iterations 0..7: row r, float4 index = lane (dwords 4*lane..4*lane+3).
    // Iteration 8: lanes 0..15 cover dwords 256..263 (2 float4/row tail).
    float4 S[9];

    auto load8 = [&](int rbase) {
#pragma unroll
        for (int r = 0; r < 8; ++r) {
            const int gy = rbase + r;
            const int gx = x0 - 4 + cd;
            float4 v = NI4;
            if ((unsigned)gy < (unsigned)ymax && (unsigned)gx < IMG_W)
                v = *(const float4*)&src[gy * IMG_W + gx];
            S[r] = v;
        }
        {   // tail: 16 active lanes, row = lane>>1, dword 256 + 4*(lane&1)
            const int gy = rbase + (lane >> 1);
            const int gx = x0 + 252 + (lane & 1) * 4;
            float4 v = NI4;
            if (lane < 16 && (unsigned)gy < (unsigned)ymax && (unsigned)gx < IMG_W)
                v = *(const float4*)&src[gy * IMG_W + gx];
            S[8] = v;
        }
    };

    auto write8 = [&](int rbase) {
#pragma unroll
        for (int r = 0; r < 8; ++r) {
            const int slot = (rbase + r) & (RING - 1);
            *(float4*)&ring[slot * ROW_DW + cd] = S[r];
        }
        if (lane < 16) {
            const int slot = (rbase + (lane >> 1)) & (RING - 1);
            *(float4*)&ring[slot * ROW_DW + 256 + (lane & 1) * 4] = S[8];
        }
    };

    // Rolling accumulators: acc slot s holds output row yo with yo%8 == s.
    // All indices below are compile-time (8-row unroll) — no scratch (rule #20).
    float acc[RING][4];
#pragma unroll
    for (int a = 0; a < RING; ++a)
#pragma unroll
        for (int l = 0; l < 4; ++l) acc[a][l] = NEG_INF;

    load8(y0 - 3);                       // prologue: first chunk in flight

    const int NIT = (STRIPE + 8) / 8;    // 5 iters: input rows y0-3 .. y0+36
#pragma unroll 1
    for (int m = 0; m < NIT; ++m) {
        const int R = y0 - 3 + m * 8;
        write8(R);                       // vmcnt-wait on S, then ds_write
        if (m + 1 < NIT) load8(R + 8);   // next chunk: full compute phase to land

#pragma unroll
        for (int u = 0; u < 8; ++u) {
            // gy = R + u ; gy % 8 == (u+5) & 7 since y0 % 8 == 0.
            const int slot = (u + 5) & 7;
            const float* rp = &ring[slot * ROW_DW + cd];
            // Window cols c0-4..c0+7 (c0 = x0+cd): 5x ds_read_b64 + 1x b32,
            // 16 B lane stride — R2/R4-measured conflict-free pattern.
            const pk2 e0 = *(const pk2*)(rp);
            const pk2 e1 = *(const pk2*)(rp + 2);
            const pk2 e2 = *(const pk2*)(rp + 4);
            const pk2 e3 = *(const pk2*)(rp + 6);
            const pk2 e4 = *(const pk2*)(rp + 8);
            const float v10 = rp[10];
            const pk2 q0 = __builtin_shufflevector(e0, e1, 1, 2);
            const pk2 q1 = __builtin_shufflevector(e1, e2, 1, 2);
            const pk2 q2 = __builtin_shufflevector(e2, e3, 1, 2);
            const pk2 q3 = __builtin_shufflevector(e3, e4, 1, 2);

            // Input row gy contributes filter row i to output row gy+3-i,
            // i.e. acc slot (u - i) & 7 (static per (u,i)).
#pragma unroll
            for (int i = 0; i < KSIZE; ++i) {
                const int a = (u - i) & 7;
                acc[a][0] = dil_body(acc[a][0], q0, q1, q2, e3.y,
                                     fp[i][0], fp[i][1], fp[i][2], f6[i]);
                acc[a][1] = dil_body(acc[a][1], e1, e2, e3, e4.x,
                                     fp[i][0], fp[i][1], fp[i][2], f6[i]);
                acc[a][2] = dil_body(acc[a][2], q1, q2, q3, e4.y,
                                     fp[i][0], fp[i][1], fp[i][2], f6[i]);
                acc[a][3] = dil_body(acc[a][3], e2, e3, e4, v10,
                                     fp[i][0], fp[i][1], fp[i][2], f6[i]);
            }

            // Retire output row yo = gy-3 (slot (u+2)&7): it just received its
            // last (i=6) contribution. Store iff yo in [y0, y0+31] — i.e.
            // k = 8m+u in [6,37] (wave-uniform scalar predicate).
            const int sret = (u + 2) & 7;
            const int k = m * 8 + u;
            if (k >= 6 && k <= 37) {
                const int yo = y0 - 6 + k;
                float4 res = make_float4(acc[sret][0], acc[sret][1],
                                         acc[sret][2], acc[sret][3]);
                *(float4*)&dst[(size_t)yo * IMG_W + (x0 + cd)] = res;
            }
            // Recycle the slot for output row gy+5 (first touched at row gy+2).
#pragma unroll
            for (int l = 0; l < 4; ++l) acc[sret][l] = NEG_INF;
        }
    }
}

extern "C" void kernel_launch(void* const* d_in, const int* in_sizes, int n_in,
                              void* d_out, int out_size, void* d_ws, size_t ws_size,
                              hipStream_t stream) {
    const float* img  = (const float*)d_in[0];
    const float* filt = (const float*)d_in[1];
    float* out = (float*)d_out;

    const int planes = in_sizes[0] / (IMG_H * IMG_W);  // B*C = 128
    dim3 grid(IMG_W / TILE_W, IMG_H / STRIPE, planes); // 2 x 16 x 128 = 4096
    dim3 block(64, 1);                                 // one wave per block
    hipLaunchKernelGGL(GrayscaleDilation2D_kernel, grid, block, 0, stream,
                       img, filt, out);
}

// Round 6
// 255.581 us; speedup vs baseline: 1.0028x; 1.0028x over previous
//
#include <hip/hip_runtime.h>

#define KSIZE 7
#define NEG_INF (-1e30f)
#define IMG_H 512
#define IMG_W 512
#define TILE_W 256             // 64 lanes x 4 cols, per wave
#define STRIPE 32              // output rows per wave
#define ROW_DW 264             // dwords per LDS row: 256 data + 4+4 halo
#define RING 8                 // LDS row ring (power of two), wave-private
#define WPB 4                  // waves per workgroup (independent, no barriers)

// <2 x float> — fadd lowers to v_pk_add_f32 (VOP3P)
typedef float pk2 __attribute__((ext_vector_type(2)));

// fmaxf(a, fmaxf(b, c)) -> v_max3_f32
#define M3(a, b, c) fmaxf((a), fmaxf((b), (c)))

static __device__ __forceinline__ pk2 mk2(float a, float b) {
    pk2 r; r.x = a; r.y = b; return r;
}

// One filter-row contribution to one output: taps t_j = v[1+l+j] + f[j].
// Max tree exactly equal in value to the scalar form.
static __device__ __forceinline__ float dil_body(float acc, pk2 a, pk2 b, pk2 c,
                                                 float t6v, pk2 f01, pk2 f23,
                                                 pk2 f45, float f6) {
    const pk2 t01 = a + f01;          // v_pk_add_f32
    const pk2 t23 = b + f23;
    const pk2 t45 = c + f45;
    const float t6 = t6v + f6;
    const float u = M3(t01.x, t01.y, t23.x);
    const float w = M3(t23.y, t45.x, t45.y);
    const float z = M3(acc, t6, u);
    return fmaxf(z, w);
}

// 4 independent waves per WG; each wave owns a private LDS ring slice and a
// private 256x32 output tile. NO __syncthreads anywhere — same-wave ds ops
// are in program order; waves touch disjoint LDS regions.
__global__ __launch_bounds__(64 * WPB)
void GrayscaleDilation2D_kernel(const float* __restrict__ img,
                                const float* __restrict__ filt,
                                float* __restrict__ out) {
    __shared__ float ring_all[WPB * RING * ROW_DW];  // 4 x 8448 B = 33792 B

    const int wy = threadIdx.y;             // wave id in WG, 0..3
    float* const ring = &ring_all[wy * (RING * ROW_DW)];

    const int plane = blockIdx.z;
    const int x0 = blockIdx.x * TILE_W;
    const int y0 = (blockIdx.y * WPB + wy) * STRIPE;  // y0 % 8 == 0
    const float* __restrict__ src = img + (size_t)plane * IMG_H * IMG_W;
    float* __restrict__ dst = out + (size_t)plane * IMG_H * IMG_W;

    const int lane = threadIdx.x;           // 0..63
    const int cd = lane * 4;                // dword base within a ring row
    // Rows fetched: y0-3 .. y0+34 (clamped). Beyond -> NEG_INF staged.
    const int ymax = (y0 + STRIPE + 3 < IMG_H) ? (y0 + STRIPE + 3) : IMG_H;

    // Filter prepacked as pairs + scalar; uniform const-index loads -> SGPRs.
    pk2 fp[KSIZE][3];
    float f6[KSIZE];
#pragma unroll
    for (int i = 0; i < KSIZE; ++i) {
        const float* fr = filt + i * KSIZE;
        fp[i][0] = mk2(fr[0], fr[1]);
        fp[i][1] = mk2(fr[2], fr[3]);
        fp[i][2] = mk2(fr[4], fr[5]);
        f6[i] = fr[6];
    }

    const float4 NI4 = make_float4(NEG_INF, NEG_INF, NEG_INF, NEG_INF);
    // Stage registers: one 8-row chunk in flight (issue-early / write-late).
    float4 S[9];

    auto load8 = [&](int rbase) {
#pragma unroll
        for (int r = 0; r < 8; ++r) {
            const int gy = rbase + r;
            const int gx = x0 - 4 + cd;
            float4 v = NI4;
            if ((unsigned)gy < (unsigned)ymax && (unsigned)gx < IMG_W)
                v = *(const float4*)&src[gy * IMG_W + gx];
            S[r] = v;
        }
        {   // tail: 16 active lanes, row = lane>>1, dword 256 + 4*(lane&1)
            const int gy = rbase + (lane >> 1);
            const int gx = x0 + 252 + (lane & 1) * 4;
            float4 v = NI4;
            if (lane < 16 && (unsigned)gy < (unsigned)ymax && (unsigned)gx < IMG_W)
                v = *(const float4*)&src[gy * IMG_W + gx];
            S[8] = v;
        }
    };

    auto write8 = [&](int rbase) {
#pragma unroll
        for (int r = 0; r < 8; ++r) {
            const int slot = (rbase + r) & (RING - 1);
            *(float4*)&ring[slot * ROW_DW + cd] = S[r];
        }
        if (lane < 16) {
            const int slot = (rbase + (lane >> 1)) & (RING - 1);
            *(float4*)&ring[slot * ROW_DW + 256 + (lane & 1) * 4] = S[8];
        }
    };

    // Rolling accumulators: acc slot s holds output row yo with yo%8 == s.
    // All indices static (8-row unroll) — no scratch (rule #20).
    float acc[RING][4];
#pragma unroll
    for (int a = 0; a < RING; ++a)
#pragma unroll
        for (int l = 0; l < 4; ++l) acc[a][l] = NEG_INF;

    load8(y0 - 3);                       // prologue: first chunk in flight

    const int NIT = (STRIPE + 8) / 8;    // 5 iters: input rows y0-3 .. y0+36
#pragma unroll 1
    for (int m = 0; m < NIT; ++m) {
        const int R = y0 - 3 + m * 8;
        write8(R);                       // vmcnt-wait on S, then ds_write
        if (m + 1 < NIT) load8(R + 8);   // next chunk: full compute phase to land

#pragma unroll
        for (int u = 0; u < 8; ++u) {
            // gy = R + u ; gy % 8 == (u+5) & 7 since y0 % 8 == 0.
            const int slot = (u + 5) & 7;
            const float* rp = &ring[slot * ROW_DW + cd];
            // Window cols c0-4..c0+7: 5x ds_read_b64 + 1x b32 — measured
            // conflict-free (R2/R4/R5: SQ_LDS_BANK_CONFLICT == 0).
            const pk2 e0 = *(const pk2*)(rp);
            const pk2 e1 = *(const pk2*)(rp + 2);
            const pk2 e2 = *(const pk2*)(rp + 4);
            const pk2 e3 = *(const pk2*)(rp + 6);
            const pk2 e4 = *(const pk2*)(rp + 8);
            const float v10 = rp[10];
            const pk2 q0 = __builtin_shufflevector(e0, e1, 1, 2);
            const pk2 q1 = __builtin_shufflevector(e1, e2, 1, 2);
            const pk2 q2 = __builtin_shufflevector(e2, e3, 1, 2);
            const pk2 q3 = __builtin_shufflevector(e3, e4, 1, 2);

            // Input row gy feeds filter row i into acc slot (u - i) & 7.
#pragma unroll
            for (int i = 0; i < KSIZE; ++i) {
                const int a = (u - i) & 7;
                acc[a][0] = dil_body(acc[a][0], q0, q1, q2, e3.y,
                                     fp[i][0], fp[i][1], fp[i][2], f6[i]);
                acc[a][1] = dil_body(acc[a][1], e1, e2, e3, e4.x,
                                     fp[i][0], fp[i][1], fp[i][2], f6[i]);
                acc[a][2] = dil_body(acc[a][2], q1, q2, q3, e4.y,
                                     fp[i][0], fp[i][1], fp[i][2], f6[i]);
                acc[a][3] = dil_body(acc[a][3], e2, e3, e4, v10,
                                     fp[i][0], fp[i][1], fp[i][2], f6[i]);
            }

            // Retire output row yo = gy-3 (slot (u+2)&7) — just got its last
            // (i=6) contribution. Store iff k = 8m+u in [6,37] (uniform).
            const int sret = (u + 2) & 7;
            const int k = m * 8 + u;
            if (k >= 6 && k <= 37) {
                const int yo = y0 - 6 + k;
                float4 res = make_float4(acc[sret][0], acc[sret][1],
                                         acc[sret][2], acc[sret][3]);
                *(float4*)&dst[(size_t)yo * IMG_W + (x0 + cd)] = res;
            }
            // Recycle the slot for output row gy+5.
#pragma unroll
            for (int l = 0; l < 4; ++l) acc[sret][l] = NEG_INF;
        }
    }
}

extern "C" void kernel_launch(void* const* d_in, const int* in_sizes, int n_in,
                              void* d_out, int out_size, void* d_ws, size_t ws_size,
                              hipStream_t stream) {
    const float* img  = (const float*)d_in[0];
    const float* filt = (const float*)d_in[1];
    float* out = (float*)d_out;

    const int planes = in_sizes[0] / (IMG_H * IMG_W);   // B*C = 128
    dim3 grid(IMG_W / TILE_W, IMG_H / (STRIPE * WPB), planes);  // 2 x 4 x 128
    dim3 block(64, WPB);                                // 256 threads, 4 waves
    hipLaunchKernelGGL(GrayscaleDilation2D_kernel, grid, block, 0, stream,
                       img, filt, out);
}